// Round 9
// baseline (284.623 us; speedup 1.0000x reference)
//
#include <hip/hip_runtime.h>

typedef unsigned short u16;
typedef unsigned int u32;
typedef _Float16 half8 __attribute__((ext_vector_type(8)));
typedef __fp16 fp16x2 __attribute__((ext_vector_type(2)));
typedef float f32x16 __attribute__((ext_vector_type(16)));

union HU { uint4 u; half8 h; };
union PK { fp16x2 h; u32 u; };

__device__ __forceinline__ u16 f2h(float f) {
  union { _Float16 h; u16 u; } c;
  c.h = (_Float16)f;
  return c.u;
}

// async global->LDS DMA, 16 B per lane (lds dest = wave-uniform base + lane*16)
typedef const __attribute__((address_space(1))) u32 gu32;
typedef __attribute__((address_space(3))) u32 lu32;
__device__ __forceinline__ void gload_lds16(const void* g, void* l) {
  __builtin_amdgcn_global_load_lds((gu32*)g, (lu32*)l, 16, 0, 0);
}

// Pack weights (O=64, I=64, 3, 3) fp32 -> fp16 in exact A-fragment order:
// wbuf[((t*2 + mt)*64 + lane)*8 + j] = w[m][c][rs]
//   m = mt*32 + (lane&31), k = t*16 + (lane>>5)*8 + j, rs = k>>6, c = k&63
// K ordering: k = rs*64 + c (rs-major, c-minor); ktile t = rs*4 + Q (16-ch quarter).
__global__ void prep_w(const float* __restrict__ w, u16* __restrict__ wbuf) {
  int idx = blockIdx.x * 256 + threadIdx.x;  // 36864 total
  int j    = idx & 7;
  int lane = (idx >> 3) & 63;
  int mt   = (idx >> 9) & 1;
  int t    = idx >> 10;
  int m  = mt * 32 + (lane & 31);
  int k  = t * 16 + (lane >> 5) * 8 + j;
  int rs = k >> 6;
  int c  = k & 63;
  wbuf[idx] = f2h(w[(m * 64 + c) * 9 + rs]);
}

// Pre-convert + pre-transpose x: fp32 NCHW -> fp16 in conv-LDS slab order:
//   xbuf[(((nb*128 + row)*8 + cblk)*128 + px)*8 + j] = fp16(x[nb][cblk*8+j][row][px])
// so the conv kernel can stage x by pure global_load_lds DMA (16 B = one px,
// 8 channels). Reads float4 along px (coalesced 1 KB/instr/wave); each lane
// converts a 4-px x 8-ch block and writes 4 consecutive uint4.
__global__ __launch_bounds__(256) void prep_x(const float* __restrict__ x,
                                              u16* __restrict__ xbuf) {
  int bid = blockIdx.x;  // 4096 = nb*128 + row
  int nb = bid >> 7, row = bid & 127;
  int tid = threadIdx.x;
  int cblk = tid >> 5;          // 0..7
  int px4 = (tid & 31) * 4;     // 0..124
  const float* xb = x + (((size_t)(nb * 64 + cblk * 8) * 128 + row) * 128 + px4);
  float4 f[8];
#pragma unroll
  for (int j = 0; j < 8; ++j) f[j] = *(const float4*)(xb + (size_t)j * 16384);
  u16* ob = xbuf + ((((size_t)(nb * 128 + row) * 8 + cblk) * 128) + px4) * 8;
#pragma unroll
  for (int p = 0; p < 4; ++p) {
    PK q0, q1, q2, q3;
    q0.h = __builtin_amdgcn_cvt_pkrtz(((const float*)&f[0])[p], ((const float*)&f[1])[p]);
    q1.h = __builtin_amdgcn_cvt_pkrtz(((const float*)&f[2])[p], ((const float*)&f[3])[p]);
    q2.h = __builtin_amdgcn_cvt_pkrtz(((const float*)&f[4])[p], ((const float*)&f[5])[p]);
    q3.h = __builtin_amdgcn_cvt_pkrtz(((const float*)&f[6])[p], ((const float*)&f[7])[p]);
    *(uint4*)(ob + p * 8) = make_uint4(q0.u, q1.u, q2.u, q3.u);
  }
}

// Implicit-GEMM conv: M = O = 64, N = pixels, K = 576 in 4 quarters of 16 ch.
// v9: PURE-DMA staging. v5-v8 all land at 97-106 us regardless of occupancy,
// buffering, reads/MFMA ratio, or register headroom — the invariant they
// share is the in-kernel fp32->fp16 staging machinery (VMEM returns ->
// pkrtz -> ds_write -> full drain barriers). This round removes it: x is
// pre-transposed to fp16 by prep_x, so BOTH x and w stage via
// global_load_lds DMA only (no VGPRs, no VALU, no ds_write).
// Per quarter Q: {issue DMA x(Q+1),w(Q+1) -> other buffers (fire-and-
// forget)} -> kloop(Q) -> barrier (drain is free: DMA completed under the
// ~3-5K-cycle kloop). 5 barriers total.
// Wave shape unchanged from v7 (proven): (rw,np) computes 64o x 64px,
// per ktile {2 A + 2 B ds_read_b128 -> 4 MFMA} = 1.0 reads/MFMA,
// acc[2][2] = 64 AGPRs. Block = 256 thr (4 waves), 2 output rows, grid 2048.
// LDS: xlds 2 x 16,640 + wlds 2 x 18,432 = 70,144 B -> 2 blocks/CU.
// OOB rows (hg 0/63) and halo slots pre-zeroed once; DMA skips OOB slabs
// (wave-uniform branch), so zeros persist across quarters.
// All LDS ops lane-contiguous 16 B -> conflict-free.
// XCD swizzle: 2048 % 8 == 0; wg = (bid&7)*256 + bid>>3.
__global__ __launch_bounds__(256, 4) void conv_mfma(
    const u16* __restrict__ xbuf, const u16* __restrict__ wbuf,
    const float* __restrict__ bias, float* __restrict__ out) {
  __shared__ u16 xlds[2][8 * 130 * 8];   // 2 x 16,640 B
  __shared__ u16 wlds[2][18 * 512];      // 2 x 18,432 B

  int tid = threadIdx.x;
  int lane = tid & 63;
  int wave = tid >> 6;  // 0..3
  int bid = blockIdx.x;
  int wg = ((bid & 7) << 8) | (bid >> 3);  // bijective XCD-contiguous remap
  int nb = wg >> 6;        // batch [0,32)
  int hg = wg & 63;        // row-group [0,64)
  int h0 = hg * 2;

  int l31 = lane & 31;
  int half = lane >> 5;
  int rw = wave >> 1;   // output row within block (0..1)
  int np = wave & 1;    // ntile pair: pixels np*64 + {0,32} + l31

  const uint4 zz = make_uint4(0u, 0u, 0u, 0u);
  // zero halo slots (0 and 129) of all 8 slabs in BOTH buffers, once.
  if (tid < 32) {
    int b = tid >> 4, sl = (tid >> 1) & 7, e = tid & 1;
    *(uint4*)&xlds[b][(sl * 130 + e * 129) * 8] = zz;
  }
  // zero OOB row-slabs (never DMA'd): hg==0 -> row 0 (slabs 0,1);
  // hg==63 -> row 3 (slabs 6,7). 520 chunks = 2 buf x 2 slab x 130 slots.
  if (hg == 0 || hg == 63) {
    int sbase = (hg == 0) ? 0 : 6;
#pragma unroll
    for (int s = 0; s < 3; ++s) {
      int i = s * 256 + tid;
      if (i < 520) {
        int b = i / 260, r = i - b * 260;
        int sl = sbase + r / 130, sp = r % 130;
        *(uint4*)&xlds[b][(sl * 130 + sp) * 8] = zz;
      }
    }
  }
  __syncthreads();  // zeros visible before any kloop (DMA skips OOB slabs)

  f32x16 acc[2][2] = {};  // [mt][ntile]

  // DMA x quarter Q (global cblks 2Q, 2Q+1; rows h0-1..h0+2) into xl.
  // 16 tasks = (row4, cblk2, 64px-half2), 4 per wave; 1 KB per instr.
  auto dma_x = [&](int Q, u16* xl) {
#pragma unroll
    for (int s = 0; s < 4; ++s) {
      int id = s * 4 + wave;     // 0..15
      int row = id >> 2;         // 0..3
      int cblk = (id >> 1) & 1;  // 0..1
      int h64 = id & 1;
      int hin = h0 - 1 + row;
      if (hin >= 0 && hin < 128) {  // wave-uniform branch
        int gc = Q * 2 + cblk;
        const u16* src =
            xbuf + ((((size_t)(nb * 128 + hin) * 8 + gc) * 128) + h64 * 64 + lane) * 8;
        gload_lds16(src, &xl[((row * 2 + cblk) * 130 + 1 + h64 * 64) * 8]);
      }
    }
  };

  // DMA quarter Q's 18 A-fragments (rs9 x mt2, 1 KB each) into wl.
  auto dma_w = [&](int Q, u16* wl) {
#pragma unroll
    for (int s5 = 0; s5 < 5; ++s5) {
      int f = s5 * 4 + wave;  // 0..19, valid < 18
      if (f < 18) {
        int gf = (f >> 1) * 8 + Q * 2 + (f & 1);  // wbuf frag (rs*4+Q)*2+mt
        gload_lds16(&wbuf[gf * 512 + lane * 8], &wl[f * 512]);
      }
    }
  };

  // 9 ktiles: per ktile {2 A + 2 B ds_read_b128, 4 MFMA} = 1.0 reads/MFMA.
  auto kloop = [&](const u16* xl, const u16* wl) {
#pragma unroll
    for (int r = 0; r < 3; ++r) {
      int row = rw + r;                 // staged row index 0..3
      int sb = (row * 2 + half) * 130;  // lane-half picks the cblk
#pragma unroll
      for (int s = 0; s < 3; ++s) {
        int rs = r * 3 + s;
        int ps = np * 64 + l31 + s;  // halo slot of ntile 0; ntile 1 at +32
        HU a0, a1, b0, b1;
        a0.u = *(const uint4*)&wl[(rs * 2 + 0) * 512 + lane * 8];
        a1.u = *(const uint4*)&wl[(rs * 2 + 1) * 512 + lane * 8];
        b0.u = *(const uint4*)&xl[(sb + ps) * 8];
        b1.u = *(const uint4*)&xl[(sb + ps + 32) * 8];
        acc[0][0] = __builtin_amdgcn_mfma_f32_32x32x16_f16(a0.h, b0.h, acc[0][0], 0, 0, 0);
        acc[0][1] = __builtin_amdgcn_mfma_f32_32x32x16_f16(a0.h, b1.h, acc[0][1], 0, 0, 0);
        acc[1][0] = __builtin_amdgcn_mfma_f32_32x32x16_f16(a1.h, b0.h, acc[1][0], 0, 0, 0);
        acc[1][1] = __builtin_amdgcn_mfma_f32_32x32x16_f16(a1.h, b1.h, acc[1][1], 0, 0, 0);
      }
    }
  };

  // ---- schedule: prologue DMA, then 4 quarters with next-quarter DMA
  //      issued before each kloop (dbuf both x and w) ----
  dma_x(0, xlds[0]);
  dma_w(0, wlds[0]);
  __syncthreads();  // drains prologue DMA
#pragma unroll
  for (int Q = 0; Q < 4; ++Q) {
    if (Q < 3) {
      dma_x(Q + 1, xlds[(Q + 1) & 1]);
      dma_w(Q + 1, wlds[(Q + 1) & 1]);
    }
    kloop(xlds[Q & 1], wlds[Q & 1]);
    if (Q < 3) __syncthreads();  // drain: DMA completed under the kloop
  }

  // ---- epilogue: C/D layout col = lane&31 (pixel), row = (reg&3)+8*(reg>>2)+4*half (o) ----
  int h = h0 + rw;
#pragma unroll
  for (int mt = 0; mt < 2; ++mt) {
#pragma unroll
    for (int i = 0; i < 2; ++i) {
      int p = np * 64 + i * 32 + l31;
      size_t ob = (size_t)nb * 64 * 16384 + (size_t)h * 128 + p;
#pragma unroll
      for (int reg = 0; reg < 16; ++reg) {
        int o = mt * 32 + (reg & 3) + 8 * (reg >> 2) + 4 * half;
        out[ob + (size_t)o * 16384] = acc[mt][i][reg] + bias[o];
      }
    }
  }
}

extern "C" void kernel_launch(void* const* d_in, const int* in_sizes, int n_in,
                              void* d_out, int out_size, void* d_ws, size_t ws_size,
                              hipStream_t stream) {
  const float* x = (const float*)d_in[0];
  const float* w = (const float*)d_in[1];
  const float* b = (const float*)d_in[2];
  float* out = (float*)d_out;
  // workspace: wbuf (73,728 B) at offset 0; xbuf (64 MB) at 128 KB offset.
  u16* wbuf = (u16*)d_ws;
  u16* xbuf = (u16*)((char*)d_ws + (128 << 10));

  prep_w<<<dim3(144), dim3(256), 0, stream>>>(w, wbuf);
  prep_x<<<dim3(4096), dim3(256), 0, stream>>>(x, xbuf);
  conv_mfma<<<dim3(2048), dim3(256), 0, stream>>>(xbuf, wbuf, b, out);
}